// Round 7
// baseline (37.958 us; speedup 1.0000x reference)
//
#include <hip/hip_runtime.h>

#define DIM   128
#define H1    20
#define NOUT  5
#define NLOAD 13     // ceil(100000 slots / 8192 waves) 1KB-loads per wave

// ---------------------------------------------------------------------------
// Kernel 1: balanced streaming scan + in-scan pre-gather.
// Work unit = 1KB slot (64 float4 / 64 lanes). 8192 waves grid-stride the
// 100000 slots: all NLOAD loads issue branch-free (indices clamped; duplicate
// reads hit the same hot line and duplicate emits write identical bytes ->
// idempotent, deterministic). A finder thread (exactly one per one-hot row)
// writes c * WV[col][:] straight into its row's partial slot: no atomics,
// no entry list, and the WV latency overlaps the machine-wide stream.
// ---------------------------------------------------------------------------
__global__ __launch_bounds__(256)
void scan_pregather(const float* __restrict__ oh,
                    const float* __restrict__ wv,
                    float4* __restrict__ part,        // [S][DIM/4]
                    int total4, int V, int nwaves, int nslots) {
    const int tid  = blockIdx.x * blockDim.x + threadIdx.x;
    const int gw   = tid >> 6;
    const int lane = tid & 63;
    const uint4* p = reinterpret_cast<const uint4*>(oh);

    uint4 v[NLOAD];
    int   fi[NLOAD];
    #pragma unroll
    for (int j = 0; j < NLOAD; ++j) {
        int s = gw + j * nwaves;
        s = (s < nslots) ? s : nslots - 1;    // clamp -> idempotent duplicates
        int f = s * 64 + lane;
        f = (f < total4) ? f : total4 - 1;
        fi[j] = f;
        v[j]  = p[f];                         // 13 independent 1KB wave-loads
    }

    unsigned acc = 0u;
    #pragma unroll
    for (int j = 0; j < NLOAD; ++j)
        acc |= (v[j].x | v[j].y) | (v[j].z | v[j].w);

    if (acc != 0u) {                          // cold: ~256 threads machine-wide
        #pragma unroll
        for (int j = 0; j < NLOAD; ++j) {
            if ((v[j].x | v[j].y) | (v[j].z | v[j].w)) {
                const float* f4 = reinterpret_cast<const float*>(&v[j]);
                #pragma unroll
                for (int k = 0; k < 4; ++k) {
                    const float c = f4[k];
                    if (c != 0.0f) {          // -0.0 correctly skipped
                        const int flat = fi[j] * 4 + k;   // < 25.6M, fits int
                        const int row  = flat / V;
                        const int col  = flat - row * V;
                        const float4* wrow =
                            reinterpret_cast<const float4*>(wv + (size_t)col * DIM);
                        float4* dst = part + (size_t)row * (DIM / 4);
                        #pragma unroll 8
                        for (int q = 0; q < DIM / 4; ++q) {
                            float4 r = wrow[q];
                            dst[q] = make_float4(c * r.x, c * r.y,
                                                 c * r.z, c * r.w);
                        }
                    }
                }
            }
        }
    }
}

// ---------------------------------------------------------------------------
// Kernel 2: fixed-order reduce of the 256x128 partials + MLP head + softmax.
// 1024 threads = 32 slices x 32 float4-lanes; each thread loads its slice's
// 8 rows in ONE independent 8-deep batch (coalesced 512B per instruction),
// then a two-stage LDS reduce in fixed order (deterministic).
// ---------------------------------------------------------------------------
__global__ __launch_bounds__(1024)
void reduce_mlp(const float4* __restrict__ part, int n,
                const float* __restrict__ W1, const float* __restrict__ b1,
                const float* __restrict__ W2, const float* __restrict__ b2,
                float* __restrict__ out) {
    __shared__ float4 sp[32][32];
    __shared__ float  sfeat[DIM];
    __shared__ float  sx[H1];
    const int tid = threadIdx.x;
    const int d4  = tid & 31;
    const int sl  = tid >> 5;                 // 0..31
    const int rps = (n + 31) >> 5;            // rows per slice (= 8)

    float4 a = make_float4(0.f, 0.f, 0.f, 0.f);
    #pragma unroll 8
    for (int r = 0; r < rps; ++r) {
        const int row = sl * rps + r;
        if (row < n) {
            float4 x = part[(size_t)row * 32 + d4];
            a.x += x.x; a.y += x.y; a.z += x.z; a.w += x.w;
        }
    }
    sp[sl][d4] = a;
    __syncthreads();

    if (tid < 32) {                            // fixed-order cross-slice reduce
        float4 s = make_float4(0.f, 0.f, 0.f, 0.f);
        #pragma unroll
        for (int q = 0; q < 32; ++q) {
            float4 x = sp[q][tid];
            s.x += x.x; s.y += x.y; s.z += x.z; s.w += x.w;
        }
        sfeat[tid * 4 + 0] = s.x; sfeat[tid * 4 + 1] = s.y;
        sfeat[tid * 4 + 2] = s.z; sfeat[tid * 4 + 3] = s.w;
    }
    __syncthreads();

    if (tid < H1) {
        float acc = b1[tid];
        #pragma unroll 8
        for (int k = 0; k < DIM; ++k)
            acc += sfeat[k] * W1[k * H1 + tid];   // W1 (128,20) row-major
        sx[tid] = fmaxf(acc, 0.0f);
    }
    __syncthreads();

    if (tid == 0) {
        float logit[NOUT];
        #pragma unroll
        for (int k = 0; k < NOUT; ++k) {
            float acc = b2[k];
            for (int j = 0; j < H1; ++j)
                acc += sx[j] * W2[j * NOUT + k];  // W2 (20,5) row-major
            logit[k] = acc;
        }
        float m = logit[0];
        #pragma unroll
        for (int k = 1; k < NOUT; ++k) m = fmaxf(m, logit[k]);
        float ex[NOUT], se = 0.f;
        #pragma unroll
        for (int k = 0; k < NOUT; ++k) { ex[k] = expf(logit[k] - m); se += ex[k]; }
        const float inv = 1.0f / se;
        #pragma unroll
        for (int k = 0; k < NOUT; ++k) out[k] = ex[k] * inv;
    }
}

extern "C" void kernel_launch(void* const* d_in, const int* in_sizes, int n_in,
                              void* d_out, int out_size, void* d_ws, size_t ws_size,
                              hipStream_t stream) {
    const float* oh = (const float*)d_in[0];   // (S, V) one-hot, f32
    const float* wv = (const float*)d_in[1];   // (V, 128) f32
    const float* W1 = (const float*)d_in[2];   // (128, 20)
    const float* b1 = (const float*)d_in[3];   // (20,)
    const float* W2 = (const float*)d_in[4];   // (20, 5)
    const float* b2 = (const float*)d_in[5];   // (5,)
    float* out = (float*)d_out;                // (5,) f32
    float4* part = (float4*)d_ws;              // S x DIM f32 partials (128 KB)

    const int V = in_sizes[1] / DIM;                  // 100000
    const long long total = (long long)in_sizes[0];   // S*V = 25.6M
    const int total4 = (int)(total / 4);               // 6.4M float4
    const int S = (int)(total / V);                    // 256

    // 2048 blocks x 256 thr = 8192 waves = exactly 32 waves/CU; each wave
    // grid-strides NLOAD 1KB slots -> per-CU work balanced to +-1 load.
    const int nslots = (total4 + 63) / 64;             // 100000
    const int nwaves = 2048 * 4;                       // 8192
    hipLaunchKernelGGL(scan_pregather, dim3(2048), dim3(256), 0, stream,
                       oh, wv, part, total4, V, nwaves, nslots);

    hipLaunchKernelGGL(reduce_mlp, dim3(1), dim3(1024), 0, stream,
                       part, S, W1, b1, W2, b2, out);
}

// Round 8
// 30.076 us; speedup vs baseline: 1.2621x; 1.2621x over previous
//
#include <hip/hip_runtime.h>

#define DIM   128
#define H1    20
#define NOUT  5
#define NLOAD 13     // ceil(100000 slots / 8192 waves) contiguous 1KB loads/wave
#define SENT  256    // sentence length

// ---------------------------------------------------------------------------
// Kernel 1: balanced streaming scan of the one-hot matrix.
// Work unit = 1KB slot (64 float4 across 64 lanes). Exactly 8192 waves
// (2048 blocks = 8/CU); wave gw owns the CONTIGUOUS slot range
// [gw*13, gw*13+13) clamped to the last slot — branch-free issue of 13
// independent 1KB loads, per-CU bytes balanced to +-1 load, per-wave
// contiguity preserved (R7 showed strided slots cost ~6us).
// For each nonzero element (value c at flat pos e): entries[e/V] = (e%V, c).
// One nonzero per one-hot row -> each slot written exactly once (duplicates
// from clamping rewrite identical bytes -> idempotent, deterministic).
// ---------------------------------------------------------------------------
__global__ __launch_bounds__(256)
void scan_collect(const float* __restrict__ oh,
                  int2* __restrict__ entries,
                  int V, int nslots) {
    const int tid  = blockIdx.x * blockDim.x + threadIdx.x;
    const int gw   = tid >> 6;
    const int lane = tid & 63;
    const uint4* p = reinterpret_cast<const uint4*>(oh);

    const int s0 = gw * NLOAD;
    uint4 v[NLOAD];
    int   sj[NLOAD];
    #pragma unroll
    for (int j = 0; j < NLOAD; ++j) {
        int s = s0 + j;
        s = (s < nslots) ? s : nslots - 1;    // clamp -> idempotent duplicates
        sj[j] = s;
        v[j]  = p[(size_t)s * 64 + lane];     // 13 independent contiguous loads
    }

    unsigned acc = 0u;
    #pragma unroll
    for (int j = 0; j < NLOAD; ++j)
        acc |= (v[j].x | v[j].y) | (v[j].z | v[j].w);

    if (acc != 0u) {                          // cold: ~256 threads machine-wide
        #pragma unroll
        for (int j = 0; j < NLOAD; ++j) {
            if ((v[j].x | v[j].y) | (v[j].z | v[j].w)) {
                const float* f4 = reinterpret_cast<const float*>(&v[j]);
                #pragma unroll
                for (int k = 0; k < 4; ++k) {
                    const float c = f4[k];
                    if (c != 0.0f) {          // -0.0 correctly skipped
                        const int flat = (sj[j] * 64 + lane) * 4 + k; // <25.6M
                        const int row  = flat / V;
                        const int col  = flat - row * V;
                        entries[row] = make_int2(col, __float_as_int(c));
                    }
                }
            }
        }
    }
}

// ---------------------------------------------------------------------------
// Kernel 2: gather + reduce + MLP head, one block of 1024 threads.
//   feature[d] = sum_e c_e * WV[col_e][d]   (fixed order -> deterministic)
//   x = relu(feature @ W1 + b1); y = softmax(x @ W2 + b2)
// d = tid&127 owns dim d; slice = tid>>7 splits entries 8 ways; unroll x4
// -> only 8 serial load batches (4 independent WV-row loads in flight each).
// ---------------------------------------------------------------------------
__global__ __launch_bounds__(1024)
void gather_mlp(const float* __restrict__ wv,
                const int2* __restrict__ entries, int n,
                const float* __restrict__ W1, const float* __restrict__ b1,
                const float* __restrict__ W2, const float* __restrict__ b2,
                float* __restrict__ out) {
    __shared__ int2  se[SENT];
    __shared__ float tmp[1024];
    __shared__ float sfeat[DIM];
    __shared__ float sx[H1];
    const int tid = threadIdx.x;

    for (int i = tid; i < n; i += 1024) se[i] = entries[i];
    __syncthreads();

    const int d     = tid & 127;
    const int slice = tid >> 7;          // 0..7

    float a0 = 0.f, a1 = 0.f, a2 = 0.f, a3 = 0.f;
    int e = slice;
    for (; e + 24 < n; e += 32) {        // 4 independent WV-row loads in flight
        const int2 e0 = se[e], e1 = se[e + 8], e2 = se[e + 16], e3 = se[e + 24];
        a0 += __int_as_float(e0.y) * wv[(size_t)e0.x * DIM + d];
        a1 += __int_as_float(e1.y) * wv[(size_t)e1.x * DIM + d];
        a2 += __int_as_float(e2.y) * wv[(size_t)e2.x * DIM + d];
        a3 += __int_as_float(e3.y) * wv[(size_t)e3.x * DIM + d];
    }
    for (; e < n; e += 8)
        a0 += __int_as_float(se[e].y) * wv[(size_t)se[e].x * DIM + d];

    tmp[tid] = (a0 + a1) + (a2 + a3);
    __syncthreads();

    if (tid < DIM) {                     // 8-way reduce per dim, fixed order
        float s = 0.f;
        #pragma unroll
        for (int k = 0; k < 8; ++k) s += tmp[d + 128 * k];
        sfeat[d] = s;
    }
    __syncthreads();

    if (tid < H1) {
        float acc = b1[tid];
        #pragma unroll 8
        for (int k = 0; k < DIM; ++k)
            acc += sfeat[k] * W1[k * H1 + tid];      // W1 (128,20) row-major
        sx[tid] = fmaxf(acc, 0.0f);
    }
    __syncthreads();

    if (tid == 0) {
        float logit[NOUT];
        #pragma unroll
        for (int k = 0; k < NOUT; ++k) {
            float a = b2[k];
            for (int j = 0; j < H1; ++j)
                a += sx[j] * W2[j * NOUT + k];       // W2 (20,5) row-major
            logit[k] = a;
        }
        float m = logit[0];
        #pragma unroll
        for (int k = 1; k < NOUT; ++k) m = fmaxf(m, logit[k]);
        float ex[NOUT], se2 = 0.f;
        #pragma unroll
        for (int k = 0; k < NOUT; ++k) { ex[k] = expf(logit[k] - m); se2 += ex[k]; }
        const float inv = 1.0f / se2;
        #pragma unroll
        for (int k = 0; k < NOUT; ++k) out[k] = ex[k] * inv;
    }
}

extern "C" void kernel_launch(void* const* d_in, const int* in_sizes, int n_in,
                              void* d_out, int out_size, void* d_ws, size_t ws_size,
                              hipStream_t stream) {
    const float* oh = (const float*)d_in[0];   // (S, V) one-hot, f32
    const float* wv = (const float*)d_in[1];   // (V, 128) f32
    const float* W1 = (const float*)d_in[2];   // (128, 20)
    const float* b1 = (const float*)d_in[3];   // (20,)
    const float* W2 = (const float*)d_in[4];   // (20, 5)
    const float* b2 = (const float*)d_in[5];   // (5,)
    float* out = (float*)d_out;                // (5,) f32
    int2* entries = (int2*)d_ws;               // S (col, coeff) slots

    const int V = in_sizes[1] / DIM;                  // 100000
    const long long total = (long long)in_sizes[0];   // S*V = 25.6M
    const int nslots = (int)(total / 4 / 64);          // 100000 1KB slots
    const int S = (int)(total / V);                    // 256

    // 2048 blocks x 256 thr = 8192 waves = exactly 8 blocks/CU; wave gw owns
    // contiguous slots [gw*13, gw*13+13) clamped (8192*13 = 106496 >= 100000).
    hipLaunchKernelGGL(scan_collect, dim3(2048), dim3(256), 0, stream,
                       oh, entries, V, nslots);

    hipLaunchKernelGGL(gather_mlp, dim3(1), dim3(1024), 0, stream,
                       wv, entries, S, W1, b1, W2, b2, out);
}